// Round 4
// baseline (622.407 us; speedup 1.0000x reference)
//
#include <hip/hip_runtime.h>

// Problem constants
#define BB 256
#define TT 512
#define DIN 128
#define HH 256
#define DOUT 64
#define X_ELEMS ((long)BB * 513 * DOUT)

typedef _Float16 half2_t __attribute__((ext_vector_type(2)));
typedef _Float16 half8_t __attribute__((ext_vector_type(8)));

static __device__ inline float fdot2f(half2_t a, half2_t b, float c) {
#if __has_builtin(__builtin_amdgcn_fdot2)
    return __builtin_amdgcn_fdot2(a, b, c, false);
#else
    return c + (float)a[0] * (float)b[0] + (float)a[1] * (float)b[1];
#endif
}

// butterfly-add across a lane quad via DPP quad_perm (XOR1 then XOR2).
// All 4 lanes of the quad end up with the full 4-lane sum. Pure VALU.
static __device__ inline float quad_bfly_add(float x) {
    int t = __builtin_amdgcn_mov_dpp(__float_as_int(x), 0xB1, 0xF, 0xF, true); // [1,0,3,2]
    x += __int_as_float(t);
    t = __builtin_amdgcn_mov_dpp(__float_as_int(x), 0x4E, 0xF, 0xF, true);     // [2,3,0,1]
    x += __int_as_float(t);
    return x;
}

// XOR-4 exchange (across the two quads of an octet) via static ds_swizzle.
static __device__ inline float xor4_add(float x) {
    int t = __builtin_amdgcn_ds_swizzle(__float_as_int(x), 0x101F); // xor lane^4
    return x + __int_as_float(t);
}

// Workgroup barrier that waits ONLY on LDS ops (lgkmcnt), not vmcnt.
// __syncthreads() emits s_waitcnt vmcnt(0) before s_barrier, which stalls on
// the inp prefetch (cold HBM ~900cy) and the h/x global stores every step.
// Those are semantically barrier-independent here: global stores are
// column-disjoint per thread and never re-read; the prefetch->LDS write is
// ordered by register dependence (compiler inserts its own vmcnt for that).
// Single asm block (no sched_barrier fences - R1's regression source): the
// memory clobber keeps ds ops ordered around it.
static __device__ inline void barrier_lds() {
    asm volatile("s_waitcnt lgkmcnt(0)\n\ts_barrier" ::: "memory");
}

// ---------------------------------------------------------------------------
// Fully fused RNN, 512 threads/block (8 waves -> 2 waves/SIMD), k-split 8.
// grid 256 (1 block/batch/CU).
// Thread (g8 = tid>>3, q8 = tid&7):
//   h-dots: 4 outputs j=4*g8..+3, k-chunk [32*q8, +32)  -> 64 dot2
//   U-dots: same 4 outputs,       k-chunk [16*q8, +16)  -> 32 dot2
//   x-dots: output g8,            k-chunk [32*q8, +32)  -> 16 dot2
// Weights fp16 in VGPRs: wh 64 + wu 32 + wo 16 = 112.
// amdgpu_waves_per_eu(2,2) pins the allocator to the 256-VGPR/2-wave plan:
// R3's launch_bounds(512,2) let it chase 4 waves/EU (VGPR_Count=124 < the
// 136 the design needs) by sinking weight loads into the loop (L2-hot, so
// invisible in FETCH_SIZE, but ~2x VALU cycles/step).
// Reduce: 2-stage DPP quad butterfly, select own accumulator, one ds_swizzle
// XOR-4. h in LDS fp16 (8 chunks of 32 @ stride 40 halves, disjoint bank
// groups), double-buffered. inp row staged in LDS fp16, double-buffered,
// prefetch depth 2. Global h/x stores deferred one step; with barrier_lds
// they and the prefetch float freely across barriers.
// ---------------------------------------------------------------------------
__global__ __attribute__((amdgpu_flat_work_group_size(512, 512),
                          amdgpu_waves_per_eu(2, 2))) void rnn_fused(
        const float* __restrict__ inp, const float* __restrict__ x0,
        const float* __restrict__ h0, const float* __restrict__ W_ih,
        const float* __restrict__ b_ih, const float* __restrict__ W_ho,
        const float* __restrict__ b_ho,
        float* __restrict__ out_x, float* __restrict__ out_h) {
    __shared__ __align__(16) _Float16 hsh[2][8][40];   // h chunks, stride 40
    __shared__ __align__(16) _Float16 ibuf[2][DIN];    // staged inp rows
    const int b = blockIdx.x;
    const int tid = threadIdx.x;
    const int g8 = tid >> 3, q8 = tid & 7, qs = q8 & 3;
    const bool hwv = (q8 < 4);     // h writer (owns j_own)
    const bool xwv = (q8 == 4);    // x writer (owns x[g8])
    const bool iwv = (tid < 64);   // inp stager

    // ---- weight preload (fp16 in VGPRs) ----
    half2_t wh[4][16];  // W_ih[4g8+jp][128 + 32q8 + 2i]
    half2_t wu[4][8];   // W_ih[4g8+jp][16q8 + 2i]
    half2_t wo[16];     // W_ho[g8][32q8 + 2i]
#pragma unroll
    for (int jp = 0; jp < 4; ++jp) {
        const float* wr = W_ih + (long)(4 * g8 + jp) * 384;
#pragma unroll
        for (int i = 0; i < 8; ++i) {
            float4 v = *(const float4*)(wr + 128 + 32 * q8 + 4 * i);
            wh[jp][2 * i]     = (half2_t){(_Float16)v.x, (_Float16)v.y};
            wh[jp][2 * i + 1] = (half2_t){(_Float16)v.z, (_Float16)v.w};
        }
#pragma unroll
        for (int i = 0; i < 4; ++i) {
            float4 v = *(const float4*)(wr + 16 * q8 + 4 * i);
            wu[jp][2 * i]     = (half2_t){(_Float16)v.x, (_Float16)v.y};
            wu[jp][2 * i + 1] = (half2_t){(_Float16)v.z, (_Float16)v.w};
        }
    }
#pragma unroll
    for (int i = 0; i < 8; ++i) {
        float4 v = *(const float4*)(W_ho + (long)g8 * HH + 32 * q8 + 4 * i);
        wo[2 * i]     = (half2_t){(_Float16)v.x, (_Float16)v.y};
        wo[2 * i + 1] = (half2_t){(_Float16)v.z, (_Float16)v.w};
    }
    const int j_own = 4 * g8 + qs;
    const float bih = b_ih[j_own];
    const float bho = b_ho[g8];

    // LDS addresses (precomputed, static per buffer)
    _Float16* hsw0 = &hsh[0][j_own >> 5][j_own & 31];
    _Float16* hsw1 = &hsh[1][j_own >> 5][j_own & 31];
    const _Float16* hsr0 = &hsh[0][q8][0];
    const _Float16* hsr1 = &hsh[1][q8][0];

    float* hrow = out_h + (long)b * 513 * HH;
    float* xrow = out_x + (long)b * 513 * DOUT;
    const float* irow = inp + (long)b * TT * DIN;

    // ---- init: h0 -> LDS buf0 + deferred reg; x0 -> deferred reg ----
    float hprev = 0.f, xprev = 0.f;
    if (hwv) {
        hprev = h0[(long)b * HH + j_own];
        *hsw0 = (_Float16)hprev;
    }
    if (xwv) xprev = x0[(long)b * DOUT + g8];
    float2 ipf = {0.f, 0.f};
    if (iwv) {
        float2 v = *(const float2*)(irow + 2 * tid);
        *(half2_t*)&ibuf[0][2 * tid] = (half2_t){(_Float16)v.x, (_Float16)v.y};
        ipf = *(const float2*)(irow + DIN + 2 * tid);   // row 1
    }
    __syncthreads();

    // initial h(0) chunk into carried regs
    half8_t hv0 = *(const half8_t*)(hsr0);
    half8_t hv1 = *(const half8_t*)(hsr0 + 8);
    half8_t hv2 = *(const half8_t*)(hsr0 + 16);
    half8_t hv3 = *(const half8_t*)(hsr0 + 24);

    const float* ipsrc = irow + 2 * DIN + 2 * tid;  // row t+2 (lanes < 64)
    float* hst = hrow + j_own;                      // deferred store: row t
    float* xst = xrow + g8;

#define HDOT(HV, C)                                                         \
    {                                                                       \
        half2_t p0 = {HV[0], HV[1]}, p1 = {HV[2], HV[3]};                   \
        half2_t p2 = {HV[4], HV[5]}, p3 = {HV[6], HV[7]};                   \
        a0 = fdot2f(p0, wh[0][4 * (C) + 0], a0);                            \
        a0 = fdot2f(p1, wh[0][4 * (C) + 1], a0);                            \
        a0 = fdot2f(p2, wh[0][4 * (C) + 2], a0);                            \
        a0 = fdot2f(p3, wh[0][4 * (C) + 3], a0);                            \
        a1 = fdot2f(p0, wh[1][4 * (C) + 0], a1);                            \
        a1 = fdot2f(p1, wh[1][4 * (C) + 1], a1);                            \
        a1 = fdot2f(p2, wh[1][4 * (C) + 2], a1);                            \
        a1 = fdot2f(p3, wh[1][4 * (C) + 3], a1);                            \
        a2 = fdot2f(p0, wh[2][4 * (C) + 0], a2);                            \
        a2 = fdot2f(p1, wh[2][4 * (C) + 1], a2);                            \
        a2 = fdot2f(p2, wh[2][4 * (C) + 2], a2);                            \
        a2 = fdot2f(p3, wh[2][4 * (C) + 3], a2);                            \
        a3 = fdot2f(p0, wh[3][4 * (C) + 0], a3);                            \
        a3 = fdot2f(p1, wh[3][4 * (C) + 1], a3);                            \
        a3 = fdot2f(p2, wh[3][4 * (C) + 2], a3);                            \
        a3 = fdot2f(p3, wh[3][4 * (C) + 3], a3);                            \
    }

#define UDOT(UV, C)                                                         \
    {                                                                       \
        half2_t p0 = {UV[0], UV[1]}, p1 = {UV[2], UV[3]};                   \
        half2_t p2 = {UV[4], UV[5]}, p3 = {UV[6], UV[7]};                   \
        a0 = fdot2f(p0, wu[0][(C) + 0], a0);                                \
        a0 = fdot2f(p1, wu[0][(C) + 1], a0);                                \
        a0 = fdot2f(p2, wu[0][(C) + 2], a0);                                \
        a0 = fdot2f(p3, wu[0][(C) + 3], a0);                                \
        a1 = fdot2f(p0, wu[1][(C) + 0], a1);                                \
        a1 = fdot2f(p1, wu[1][(C) + 1], a1);                                \
        a1 = fdot2f(p2, wu[1][(C) + 2], a1);                                \
        a1 = fdot2f(p3, wu[1][(C) + 3], a1);                                \
        a2 = fdot2f(p0, wu[2][(C) + 0], a2);                                \
        a2 = fdot2f(p1, wu[2][(C) + 1], a2);                                \
        a2 = fdot2f(p2, wu[2][(C) + 2], a2);                                \
        a2 = fdot2f(p3, wu[2][(C) + 3], a2);                                \
        a3 = fdot2f(p0, wu[3][(C) + 0], a3);                                \
        a3 = fdot2f(p1, wu[3][(C) + 1], a3);                                \
        a3 = fdot2f(p2, wu[3][(C) + 2], a3);                                \
        a3 = fdot2f(p3, wu[3][(C) + 3], a3);                                \
    }

#define XDOT(HV, C)                                                         \
    {                                                                       \
        ax = fdot2f((half2_t){HV[0], HV[1]}, wo[4 * (C) + 0], ax);          \
        ax = fdot2f((half2_t){HV[2], HV[3]}, wo[4 * (C) + 1], ax);          \
        ax = fdot2f((half2_t){HV[4], HV[5]}, wo[4 * (C) + 2], ax);          \
        ax = fdot2f((half2_t){HV[6], HV[7]}, wo[4 * (C) + 3], ax);          \
    }

// One recurrence step. T = step index, PC = current parity buf, PN = next.
// HRD = LDS read base for h(T+1), HWD = LDS write addr for h(T+1).
#define STEP(T, PC, PN, HRD, HWD)                                           \
    {                                                                       \
        /* deferred global stores from previous step (row T) */             \
        if (hwv) hst[0] = hprev;                                            \
        if (xwv) xst[0] = xprev;                                            \
        hst += HH; xst += DOUT;                                             \
        /* prefetch inp row T+2 (floats across the whole step) */           \
        float2 ipn = {0.f, 0.f};                                            \
        if (iwv && (T) + 2 < TT) ipn = *(const float2*)ipsrc;               \
        ipsrc += DIN;                                                       \
        /* U chunk from staged row T */                                     \
        const _Float16* ib = &ibuf[PC][16 * q8];                            \
        half8_t uv0 = *(const half8_t*)(ib);                                \
        half8_t uv1 = *(const half8_t*)(ib + 8);                            \
        float a0 = 0.f, a1 = 0.f, a2 = 0.f, a3 = 0.f;                       \
        HDOT(hv0, 0) HDOT(hv1, 1) HDOT(hv2, 2) HDOT(hv3, 3)                 \
        UDOT(uv0, 0) UDOT(uv1, 4)                                           \
        a0 = quad_bfly_add(a0);                                             \
        a1 = quad_bfly_add(a1);                                             \
        a2 = quad_bfly_add(a2);                                             \
        a3 = quad_bfly_add(a3);                                             \
        float sp = (qs == 0) ? a0 : (qs == 1) ? a1 : (qs == 2) ? a2 : a3;   \
        float s = xor4_add(sp);                                             \
        float tot = s + bih;                                                \
        float hn = tot >= 0.f ? tot : 0.01f * tot;                          \
        if (hwv) *(HWD) = (_Float16)hn;                                     \
        if (iwv) *(half2_t*)&ibuf[PN][2 * tid] =                            \
            (half2_t){(_Float16)ipf.x, (_Float16)ipf.y};                    \
        ipf = ipn;                                                          \
        hprev = hn;                                                         \
        barrier_lds();                                                      \
        /* read h(T+1) chunk: feeds x(T+1) now and h-dots next step */      \
        hv0 = *(const half8_t*)(HRD);                                       \
        hv1 = *(const half8_t*)(HRD + 8);                                   \
        hv2 = *(const half8_t*)(HRD + 16);                                  \
        hv3 = *(const half8_t*)(HRD + 24);                                  \
        float ax = 0.f;                                                     \
        XDOT(hv0, 0) XDOT(hv1, 1) XDOT(hv2, 2) XDOT(hv3, 3)                 \
        ax = quad_bfly_add(ax);                                             \
        ax = xor4_add(ax);                                                  \
        xprev = ax + bho;                                                   \
    }

    for (int t = 0; t < TT; t += 2) {
        STEP(t,     0, 1, hsr1, hsw1)
        STEP(t + 1, 1, 0, hsr0, hsw0)
    }
    // final deferred stores: row 512
    if (hwv) hst[0] = hprev;
    if (xwv) xst[0] = xprev;

#undef STEP
#undef HDOT
#undef UDOT
#undef XDOT
}

extern "C" void kernel_launch(void* const* d_in, const int* in_sizes, int n_in,
                              void* d_out, int out_size, void* d_ws, size_t ws_size,
                              hipStream_t stream) {
    const float* inp  = (const float*)d_in[0];
    const float* x0   = (const float*)d_in[1];
    const float* h0   = (const float*)d_in[2];
    const float* W_ih = (const float*)d_in[3];
    const float* b_ih = (const float*)d_in[4];
    const float* W_ho = (const float*)d_in[5];
    const float* b_ho = (const float*)d_in[6];
    float* out_x = (float*)d_out;
    float* out_h = out_x + X_ELEMS;

    rnn_fused<<<dim3(256), 512, 0, stream>>>(inp, x0, h0, W_ih, b_ih, W_ho, b_ho,
                                             out_x, out_h);
}

// Round 5
// 547.370 us; speedup vs baseline: 1.1371x; 1.1371x over previous
//
#include <hip/hip_runtime.h>

// Problem constants
#define BB 256
#define TT 512
#define DIN 128
#define HH 256
#define DOUT 64
#define X_ELEMS ((long)BB * 513 * DOUT)

typedef short bf16x8 __attribute__((ext_vector_type(8)));
typedef float f32x4 __attribute__((ext_vector_type(4)));
typedef _Float16 half2_t __attribute__((ext_vector_type(2)));
typedef _Float16 half4_t __attribute__((ext_vector_type(4)));
typedef _Float16 half8_t __attribute__((ext_vector_type(8)));

static __device__ inline short f2bf(float f) {
    unsigned u = __float_as_uint(f);
    unsigned r = (u + 0x7FFFu + ((u >> 16) & 1u)) >> 16;
    return (short)r;
}

static __device__ inline float fdot2f(half2_t a, half2_t b, float c) {
#if __has_builtin(__builtin_amdgcn_fdot2)
    return __builtin_amdgcn_fdot2(a, b, c, false);
#else
    return c + (float)a[0] * (float)b[0] + (float)a[1] * (float)b[1];
#endif
}

static __device__ inline float dpp_xor1(float x) {  // quad_perm [1,0,3,2]
    return __int_as_float(
        __builtin_amdgcn_mov_dpp(__float_as_int(x), 0xB1, 0xF, 0xF, true));
}
static __device__ inline float dpp_xor2(float x) {  // quad_perm [2,3,0,1]
    return __int_as_float(
        __builtin_amdgcn_mov_dpp(__float_as_int(x), 0x4E, 0xF, 0xF, true));
}
static __device__ inline float swz_xor4(float x) {
    return __int_as_float(
        __builtin_amdgcn_ds_swizzle(__float_as_int(x), 0x101F));
}
static __device__ inline float swz_xor8(float x) {
    return __int_as_float(
        __builtin_amdgcn_ds_swizzle(__float_as_int(x), 0x201F));
}

// ---------------------------------------------------------------------------
// Recurrence kernel (U fused from LDS-staged inp; x done by gemm_x after).
// grid 256 (1 block/batch/CU), block 512 (8 waves, 2 waves/SIMD).
// Thread (g = tid>>4, q = tid&15): 8 outputs j = 8g..8g+7, k-slice 16.
//   h-dots: h[16q..16q+16)   -> 8  fdot2 per output
//   U-dots: u[8q..8q+8)      -> 4  fdot2 per output      (96 fdot2 total)
// LDS read per step: 32B(h) + 16B(U) per thread = 24.5 KB/CU (~290 cy pipe)
// vs 49-96 KB in R2-R4 designs (the hidden LDS-pipe bottleneck).
// Reduce: 4-stage select-tree (XOR1/XOR2 via DPP, XOR4/XOR8 via ds_swizzle);
// lane (g,q) ends with the FULL sum of output j=8g+(q&7); lanes q<8 write.
// Weights fp16 in VGPRs (wh 64 + wu 32 = 96), PINNED with volatile asm so
// the compiler cannot rematerialize the load+cvt inside the loop (R2-R4:
// VGPR_Count=124 < design minimum proved remat; ~2x VALU cycles/step).
// h LDS layout: 16 chunks of 16 halves, stride 24 halves (48B): chunk bases
// hit banks 12q mod 32 -> only q/q+8 alias = 2-way conflict (free, m136),
// and 48B keeps b128 alignment. ibuf: 16 chunks stride 12 halves (24B),
// half4 reads, bases on banks 6q mod 32 -> conflict-free.
// Global h stores deferred one step; inp prefetch depth 2.
// ---------------------------------------------------------------------------
__global__ __launch_bounds__(512, 2) void rnn_seq(
        const float* __restrict__ inp, const float* __restrict__ x0,
        const float* __restrict__ h0, const float* __restrict__ W_ih,
        const float* __restrict__ b_ih,
        float* __restrict__ out_x, float* __restrict__ out_h) {
    __shared__ __align__(16) _Float16 hsh[2][16][24];  // h chunks
    __shared__ __align__(16) _Float16 ibuf[2][16][12]; // staged inp rows
    const int b = blockIdx.x;
    const int tid = threadIdx.x;
    const int g = tid >> 4, q = tid & 15;
    const int j = 8 * g + (q & 7);        // output this lane ends up holding
    const bool hwv = (q < 8);             // h writer
    const bool iwv = (tid < 64);          // inp stager

    // ---- weight preload (fp16 in VGPRs), then PIN ----
    half2_t wh[8][8];   // W_ih[8g+jp][128 + 16q + 2i]
    half2_t wu[8][4];   // W_ih[8g+jp][8q + 2i]
#pragma unroll
    for (int jp = 0; jp < 8; ++jp) {
        const float* wr = W_ih + (long)(8 * g + jp) * 384;
#pragma unroll
        for (int m = 0; m < 4; ++m) {
            float4 v = *(const float4*)(wr + 128 + 16 * q + 4 * m);
            wh[jp][2 * m]     = (half2_t){(_Float16)v.x, (_Float16)v.y};
            wh[jp][2 * m + 1] = (half2_t){(_Float16)v.z, (_Float16)v.w};
        }
#pragma unroll
        for (int m = 0; m < 2; ++m) {
            float4 v = *(const float4*)(wr + 8 * q + 4 * m);
            wu[jp][2 * m]     = (half2_t){(_Float16)v.x, (_Float16)v.y};
            wu[jp][2 * m + 1] = (half2_t){(_Float16)v.z, (_Float16)v.w};
        }
    }
    // Pin: volatile asm cannot be rematerialized -> weights stay resident.
#pragma unroll
    for (int jp = 0; jp < 8; ++jp) {
#pragma unroll
        for (int i = 0; i < 8; ++i) asm volatile("" : "+v"(wh[jp][i]));
#pragma unroll
        for (int i = 0; i < 4; ++i) asm volatile("" : "+v"(wu[jp][i]));
    }
    const float bih = b_ih[j];

    float* hrow = out_h + (long)b * 513 * HH;
    float* xrow = out_x + (long)b * 513 * DOUT;
    const float* irow = inp + (long)b * TT * DIN;

    // ---- init ----
    float hprev = 0.f;
    if (hwv) {
        hprev = h0[(long)b * HH + j];           // deferred store -> row 0
        hsh[0][j >> 4][j & 15] = (_Float16)hprev;
    }
    if (tid < DOUT) xrow[tid] = x0[(long)b * DOUT + tid];
    float2 ipf = {0.f, 0.f};
    if (iwv) {
        float2 v = *(const float2*)(irow + 2 * tid);          // row 0
        *(half2_t*)&ibuf[0][tid >> 2][2 * (tid & 3)] =
            (half2_t){(_Float16)v.x, (_Float16)v.y};
        ipf = *(const float2*)(irow + DIN + 2 * tid);         // row 1
    }
    __syncthreads();

    // carried h(0) slice
    half8_t hva = *(const half8_t*)&hsh[0][q][0];
    half8_t hvb = *(const half8_t*)&hsh[0][q][8];

    const float* ipsrc = irow + 2 * DIN + 2 * tid;  // row t+2 (lanes < 64)
    float* hst = hrow + j;                          // deferred store: row t

#define STEP(T, PC, PN)                                                     \
    {                                                                       \
        /* deferred global h store from previous step (row T) */            \
        if (hwv) hst[0] = hprev;                                            \
        hst += HH;                                                          \
        /* prefetch inp row T+2 */                                          \
        float2 ipn = {0.f, 0.f};                                            \
        if (iwv && (T) + 2 < TT) ipn = *(const float2*)ipsrc;               \
        ipsrc += DIN;                                                       \
        /* U slice from staged row T */                                     \
        half4_t uva = *(const half4_t*)&ibuf[PC][q][0];                     \
        half4_t uvb = *(const half4_t*)&ibuf[PC][q][4];                     \
        half2_t hp0 = {hva[0], hva[1]}, hp1 = {hva[2], hva[3]};             \
        half2_t hp2 = {hva[4], hva[5]}, hp3 = {hva[6], hva[7]};             \
        half2_t hp4 = {hvb[0], hvb[1]}, hp5 = {hvb[2], hvb[3]};             \
        half2_t hp6 = {hvb[4], hvb[5]}, hp7 = {hvb[6], hvb[7]};             \
        half2_t up0 = {uva[0], uva[1]}, up1 = {uva[2], uva[3]};             \
        half2_t up2 = {uvb[0], uvb[1]}, up3 = {uvb[2], uvb[3]};             \
        float r[8];                                                         \
        _Pragma("unroll")                                                   \
        for (int jp = 0; jp < 8; ++jp) {                                    \
            float a = 0.f;                                                  \
            a = fdot2f(hp0, wh[jp][0], a);                                  \
            a = fdot2f(hp1, wh[jp][1], a);                                  \
            a = fdot2f(hp2, wh[jp][2], a);                                  \
            a = fdot2f(hp3, wh[jp][3], a);                                  \
            a = fdot2f(hp4, wh[jp][4], a);                                  \
            a = fdot2f(hp5, wh[jp][5], a);                                  \
            a = fdot2f(hp6, wh[jp][6], a);                                  \
            a = fdot2f(hp7, wh[jp][7], a);                                  \
            a = fdot2f(up0, wu[jp][0], a);                                  \
            a = fdot2f(up1, wu[jp][1], a);                                  \
            a = fdot2f(up2, wu[jp][2], a);                                  \
            a = fdot2f(up3, wu[jp][3], a);                                  \
            r[jp] = a;                                                      \
        }                                                                   \
        /* 4-stage reduce-select tree: lane ends with output 8g+(q&7) */    \
        float s, k;                                                         \
        s = (q & 1) ? r[0] : r[1]; k = (q & 1) ? r[1] : r[0];               \
        float n0 = k + dpp_xor1(s);                                         \
        s = (q & 1) ? r[2] : r[3]; k = (q & 1) ? r[3] : r[2];               \
        float n1 = k + dpp_xor1(s);                                         \
        s = (q & 1) ? r[4] : r[5]; k = (q & 1) ? r[5] : r[4];               \
        float n2 = k + dpp_xor1(s);                                         \
        s = (q & 1) ? r[6] : r[7]; k = (q & 1) ? r[7] : r[6];               \
        float n3 = k + dpp_xor1(s);                                         \
        s = (q & 2) ? n0 : n1; k = (q & 2) ? n1 : n0;                       \
        float m0 = k + dpp_xor2(s);                                         \
        s = (q & 2) ? n2 : n3; k = (q & 2) ? n3 : n2;                       \
        float m1 = k + dpp_xor2(s);                                         \
        s = (q & 4) ? m0 : m1; k = (q & 4) ? m1 : m0;                       \
        float v8 = k + swz_xor4(s);                                         \
        float sum = v8 + swz_xor8(v8);                                      \
        float tot = sum + bih;                                              \
        float hn = tot >= 0.f ? tot : 0.01f * tot;   /* LeakyReLU */        \
        if (hwv) hsh[PN][j >> 4][j & 15] = (_Float16)hn;                    \
        if (iwv) *(half2_t*)&ibuf[PN][tid >> 2][2 * (tid & 3)] =            \
            (half2_t){(_Float16)ipf.x, (_Float16)ipf.y};                    \
        ipf = ipn;                                                          \
        hprev = hn;                                                         \
        __syncthreads();                                                    \
        /* read h(T+1): feeds next step's dots */                           \
        hva = *(const half8_t*)&hsh[PN][q][0];                              \
        hvb = *(const half8_t*)&hsh[PN][q][8];                              \
    }

    for (int t = 0; t < TT; t += 2) {
        STEP(t,     0, 1)
        STEP(t + 1, 1, 0)
    }
    // final deferred store: row 512
    if (hwv) hst[0] = hprev;
#undef STEP
}

// ---------------------------------------------------------------------------
// Kernel C: x[b,t,:] = h[b,t,:] @ W_ho^T + b_ho, t=1..512.
// Full-K (256) staging, ONE barrier. grid 2048, block 256. Tile M64 x N64.
// (verified structure from the R0 baseline)
// ---------------------------------------------------------------------------
#define SX 264  // LDS row stride (shorts) for K=256: 528 B, 16-aligned
__global__ __launch_bounds__(256) void gemm_x(
        const float* __restrict__ out_h, const float* __restrict__ W_ho,
        const float* __restrict__ b_ho, float* __restrict__ out_x) {
    __shared__ __align__(16) short lA[64 * SX];
    __shared__ __align__(16) short lB[64 * SX];
    const int tid = threadIdx.x;
    const int wave = tid >> 6, lane = tid & 63;
    const int quad = lane >> 4, l16 = lane & 15;
    const int m0 = blockIdx.x * 64;
    const int bb = m0 >> 9, t0 = m0 & 511;
    const float* hsrc = out_h + ((long)bb * 513 + 1 + t0) * HH;
    float* xdst = out_x + ((long)bb * 513 + 1 + t0) * DOUT;
    const int sm = tid >> 2, skg = tid & 3;
    const int sn = tid & 63, bkg = tid >> 6;

#pragma unroll
    for (int ph = 0; ph < 2; ++ph) {   // two phases of 4 k-chunks to cap regs
        float4 a4[8], b4[8];
#pragma unroll
        for (int c = 0; c < 4; ++c) {
            int k0 = ph * 128 + c * 32;
            const float4* ap = (const float4*)(hsrc + (long)sm * HH + k0 + skg * 8);
            a4[2 * c] = ap[0]; a4[2 * c + 1] = ap[1];
            const float4* bp = (const float4*)(W_ho + (long)sn * HH + k0 + bkg * 8);
            b4[2 * c] = bp[0]; b4[2 * c + 1] = bp[1];
        }
#pragma unroll
        for (int c = 0; c < 4; ++c) {
            int k0 = ph * 128 + c * 32;
            bf16x8 av, bv;
            float4 x0v = a4[2 * c], x1v = a4[2 * c + 1];
            av[0] = f2bf(x0v.x); av[1] = f2bf(x0v.y); av[2] = f2bf(x0v.z); av[3] = f2bf(x0v.w);
            av[4] = f2bf(x1v.x); av[5] = f2bf(x1v.y); av[6] = f2bf(x1v.z); av[7] = f2bf(x1v.w);
            float4 y0 = b4[2 * c], y1 = b4[2 * c + 1];
            bv[0] = f2bf(y0.x); bv[1] = f2bf(y0.y); bv[2] = f2bf(y0.z); bv[3] = f2bf(y0.w);
            bv[4] = f2bf(y1.x); bv[5] = f2bf(y1.y); bv[6] = f2bf(y1.z); bv[7] = f2bf(y1.w);
            *(bf16x8*)&lA[sm * SX + k0 + skg * 8] = av;
            *(bf16x8*)&lB[sn * SX + k0 + bkg * 8] = bv;
        }
    }
    __syncthreads();

    f32x4 acc[4];
#pragma unroll
    for (int i = 0; i < 4; i++) acc[i] = (f32x4){0.f, 0.f, 0.f, 0.f};
#pragma unroll
    for (int c = 0; c < 8; ++c) {
        bf16x8 af = *(const bf16x8*)&lA[(wave * 16 + l16) * SX + c * 32 + quad * 8];
#pragma unroll
        for (int nt = 0; nt < 4; ++nt) {
            bf16x8 bf = *(const bf16x8*)&lB[(nt * 16 + l16) * SX + c * 32 + quad * 8];
            acc[nt] = __builtin_amdgcn_mfma_f32_16x16x32_bf16(af, bf, acc[nt], 0, 0, 0);
        }
    }
#pragma unroll
    for (int nt = 0; nt < 4; ++nt) {
#pragma unroll
        for (int r = 0; r < 4; ++r) {
            int mr = wave * 16 + quad * 4 + r;
            int col = nt * 16 + l16;
            xdst[(long)mr * DOUT + col] = acc[nt][r] + b_ho[col];
        }
    }
}

extern "C" void kernel_launch(void* const* d_in, const int* in_sizes, int n_in,
                              void* d_out, int out_size, void* d_ws, size_t ws_size,
                              hipStream_t stream) {
    const float* inp  = (const float*)d_in[0];
    const float* x0   = (const float*)d_in[1];
    const float* h0   = (const float*)d_in[2];
    const float* W_ih = (const float*)d_in[3];
    const float* b_ih = (const float*)d_in[4];
    const float* W_ho = (const float*)d_in[5];
    const float* b_ho = (const float*)d_in[6];
    float* out_x = (float*)d_out;
    float* out_h = out_x + X_ELEMS;

    rnn_seq<<<dim3(256), 512, 0, stream>>>(inp, x0, h0, W_ih, b_ih, out_x, out_h);
    gemm_x<<<dim3(2048), 256, 0, stream>>>(out_h, W_ho, b_ho, out_x);
}